// Round 3
// baseline (159.710 us; speedup 1.0000x reference)
//
#include <hip/hip_runtime.h>
#include <hip/hip_bf16.h>

// KAN harmonic-basis GEMM, v6: register-direct A-gen + K-split-2 for occupancy.
// out[b,h] = sum_{d,f} basis(x[b,d])[f] * W[d,f,h] + sum_d b[d,h]
//
// f=0 + bias -> fp32 partials c_part[8][256], summed in GEMM epilogue.
// f=1..10    -> bf16 MFMA GEMM, M=16384, N=256, K=2560.
//
// v6 (v5 post-mortem: VGPR=80 proved the compiler collapsed the depth-4
// register pipeline again; occupancy pinned at 2 waves/SIMD by the grid ->
// latency-bound at ~57us with both pipes <25%):
//   - K-split-2: 512-thread blocks, 8 waves. Waves 0-3 handle dtiles 0-3,
//     waves 4-7 handle dtiles 4-7 (flat kt halves). Same 64x128 block tile.
//     Grid stays 512 blocks -> 4096 waves -> 4 waves/SIMD (2x TLP).
//     Per-CU B-traffic/VALU/MFMA totals unchanged (per-wave work halves).
//   - Main loop unchanged from v5: barrier-free, LDS-free, each lane
//     generates its own A fragment (sincos + Chebyshev), depth-4 B buffer
//     (compiler will shallow it; TLP now hides the latency instead).
//   - End combine: each K-half wave gives one i-frag via 32KB LDS, keeps the
//     other; ONE __syncthreads total. kh branches are wave-uniform (no
//     runtime-indexed register arrays -> no scratch).
//   - __launch_bounds__(512,4) caps VGPR at 128 for 2 blocks/CU.

#define BDIM 16384
#define DDIM 256
#define HOUT 256
#define NKT  80
#define BM 64
#define BN 128

typedef __bf16 bf16x8 __attribute__((ext_vector_type(8)));
typedef float floatx4 __attribute__((ext_vector_type(4)));

__device__ __forceinline__ unsigned short f2bf(float f) {
    unsigned int u = __float_as_uint(f);
    return (unsigned short)((u + 0x7FFFu + ((u >> 16) & 1u)) >> 16);
}

__device__ __forceinline__ unsigned int pkbf(float a, float b) {
    __hip_bfloat162 r = __float22bfloat162_rn(make_float2(a, b));
    return *reinterpret_cast<unsigned int*>(&r);
}

// grid 328 x 256 threads.
// blocks [0,320): kt = bid>>2, sub = bid&3:
//   Wfrag[kt][n=t][dd = sub*8 .. +8] = bf16(W[dtile*32+dd][kt%10+1][n])
// blocks [320,328): p = bid-320; c_part[p][h] = sum_{d in p*32..+32} W[d][0][h]+b[d][h]
__global__ void prep_kernel(const float* __restrict__ W, const float* __restrict__ bias,
                            unsigned short* __restrict__ Wfrag, float* __restrict__ c_part) {
    const int bid = blockIdx.x;
    const int t = threadIdx.x;
    if (bid < 4 * NKT) {
        const int kt = bid >> 2;
        const int sub = bid & 3;
        const int dtile = kt / 10;
        const int f = kt - dtile * 10 + 1;
        const int d0 = dtile * 32 + sub * 8;
        const float* wsrc = W + ((size_t)d0 * 11 + f) * 256 + t;
        union { unsigned short s[8]; int4 v; } buf;
#pragma unroll
        for (int dd = 0; dd < 8; ++dd)
            buf.s[dd] = f2bf(wsrc[(size_t)dd * 11 * 256]);
        *(int4*)(Wfrag + ((size_t)kt * 256 + t) * 32 + sub * 8) = buf.v;
    } else {
        const int p = bid - 4 * NKT;
        float acc = 0.f;
#pragma unroll
        for (int dd = 0; dd < 32; ++dd) {
            const int d = p * 32 + dd;
            acc += W[(size_t)(d * 11) * 256 + t] + bias[(size_t)d * 256 + t];
        }
        c_part[p * 256 + t] = acc;
    }
}

__global__ __launch_bounds__(512, 4)
void kan_gemm(const float* __restrict__ x, const unsigned short* __restrict__ Wfrag,
              const float* __restrict__ c_part, float* __restrict__ out) {
    __shared__ float red[4][2][4][256];   // 32 KB: [pair][i-frag][j][lane*4]

    const int t = threadIdx.x;
    const int m0 = blockIdx.x * BM;
    const int h0 = blockIdx.y * BN;

    const int lane = t & 63;
    const int wave = t >> 6;         // 0..7
    const int kh = wave >> 2;        // K-half: dtiles kh*4 .. kh*4+3
    const int w4 = wave & 3;         // pair id (partner = w4 + 4*(1-kh))
    const int wr = (wave >> 1) & 1;  // row half (32 rows)
    const int wc = wave & 1;         // col half (64 cols)
    const int l15 = lane & 15;
    const int koff = lane >> 4;

    floatx4 acc[2][4];
#pragma unroll
    for (int i = 0; i < 2; ++i)
#pragma unroll
        for (int j = 0; j < 4; ++j)
            acc[i][j] = (floatx4){0.f, 0.f, 0.f, 0.f};

    // lane's x rows: i=0 -> m0 + wr*32 + l15, i=1 -> +16; d-slots koff*8..+8
    const float* xr0 = x + (size_t)(m0 + wr * 32 + l15) * DDIM + koff * 8 + kh * 128;
    const unsigned short* bbase = Wfrag + (size_t)kh * 40 * 8192
                                + (size_t)(h0 + wc * 64 + l15) * 32 + koff * 8;

    // x for first dtile of this K-half: [i*2 + half4]
    float4 xc[4];
    xc[0] = *(const float4*)(xr0 + 0);
    xc[1] = *(const float4*)(xr0 + 4);
    xc[2] = *(const float4*)(xr0 + 16 * DDIM + 0);
    xc[3] = *(const float4*)(xr0 + 16 * DDIM + 4);

    // B prologue: local kt = 0..3 in flight (depth-4 rolling buffer, slot = kt&3)
    bf16x8 bf[4][4];
#pragma unroll
    for (int p = 0; p < 4; ++p)
#pragma unroll
        for (int j = 0; j < 4; ++j)
            bf[p][j] = *(const bf16x8*)(bbase + (size_t)p * 8192 + j * 512);

#pragma unroll
    for (int dt = 0; dt < 4; ++dt) {
        // x prefetch for next dtile (issued early, consumed next iteration)
        float4 xn[4];
        if (dt < 3) {
            xn[0] = *(const float4*)(xr0 + (dt + 1) * 32 + 0);
            xn[1] = *(const float4*)(xr0 + (dt + 1) * 32 + 4);
            xn[2] = *(const float4*)(xr0 + 16 * DDIM + (dt + 1) * 32 + 0);
            xn[3] = *(const float4*)(xr0 + 16 * DDIM + (dt + 1) * 32 + 4);
        }

        // ---- gen init: sincos of 16 elems; Chebyshev state ----
        float sc[16], cc[16], sp[16], cp[16], t2c[16];
#pragma unroll
        for (int i = 0; i < 2; ++i)
#pragma unroll
            for (int e = 0; e < 8; ++e) {
                const int g = i * 8 + e;
                const float xv = ((const float*)&xc[i * 2 + (e >> 2)])[e & 3];
                __sincosf(xv, &sc[g], &cc[g]);
                t2c[g] = cc[g] + cc[g];
                sp[g] = 0.f;
                cp[g] = 1.f;
            }

        // ---- fused pack -> MFMA -> B refill -> recurrence, hs = 0..9 ----
#pragma unroll
        for (int hs = 0; hs < 10; ++hs) {
            const int cur = (dt * 10 + hs) & 3;      // compile-time (full unroll)
            const float* src = (hs & 1) ? cc : sc;   // even: sin(k), odd: cos(k)

            union { unsigned int u[4]; bf16x8 v; } a0, a1;
#pragma unroll
            for (int p = 0; p < 4; ++p) {
                a0.u[p] = pkbf(src[2 * p], src[2 * p + 1]);
                a1.u[p] = pkbf(src[8 + 2 * p], src[8 + 2 * p + 1]);
            }
#pragma unroll
            for (int j = 0; j < 4; ++j) {
                acc[0][j] = __builtin_amdgcn_mfma_f32_16x16x32_bf16(a0.v, bf[cur][j], acc[0][j], 0, 0, 0);
                acc[1][j] = __builtin_amdgcn_mfma_f32_16x16x32_bf16(a1.v, bf[cur][j], acc[1][j], 0, 0, 0);
            }

            // B refill: local kt + 4 into the slot just consumed (clamped in-half)
            {
                int ktl = dt * 10 + hs + 4;
                if (ktl > 39) ktl = 39;
#pragma unroll
                for (int j = 0; j < 4; ++j)
                    bf[cur][j] = *(const bf16x8*)(bbase + (size_t)ktl * 8192 + j * 512);
            }

            // advance Chebyshev after each cos step (except the last)
            if ((hs & 1) && hs < 9) {
#pragma unroll
                for (int g = 0; g < 16; ++g) {
                    const float ns = t2c[g] * sc[g] - sp[g];
                    const float nc = t2c[g] * cc[g] - cp[g];
                    sp[g] = sc[g]; cp[g] = cc[g];
                    sc[g] = ns;   cc[g] = nc;
                }
            }
        }

        if (dt < 3) {
            xc[0] = xn[0]; xc[1] = xn[1]; xc[2] = xn[2]; xc[3] = xn[3];
        }
    }

    // ---- cross-half combine: kh=0 gives i=1 / keeps i=0; kh=1 the reverse ----
    if (kh == 0) {
#pragma unroll
        for (int j = 0; j < 4; ++j)
            *(floatx4*)&red[w4][1][j][lane * 4] = acc[1][j];
    } else {
#pragma unroll
        for (int j = 0; j < 4; ++j)
            *(floatx4*)&red[w4][0][j][lane * 4] = acc[0][j];
    }

    // bias partials (independent of LDS exchange)
    float cj[4];
#pragma unroll
    for (int j = 0; j < 4; ++j) {
        const int col = h0 + wc * 64 + j * 16 + l15;
        float s = 0.f;
#pragma unroll
        for (int p = 0; p < 8; ++p) s += c_part[p * 256 + col];
        cj[j] = s;
    }

    __syncthreads();

    // ---- epilogue: C/D layout col=lane&15, row=(lane>>4)*4+reg ----
    if (kh == 0) {
        const int row0 = m0 + wr * 32 + koff * 4;            // i=0 rows
#pragma unroll
        for (int j = 0; j < 4; ++j) {
            const int col = h0 + wc * 64 + j * 16 + l15;
            const floatx4 v = *(const floatx4*)&red[w4][0][j][lane * 4];
#pragma unroll
            for (int r = 0; r < 4; ++r)
                out[(size_t)(row0 + r) * HOUT + col] = acc[0][j][r] + v[r] + cj[j];
        }
    } else {
        const int row0 = m0 + wr * 32 + 16 + koff * 4;       // i=1 rows
#pragma unroll
        for (int j = 0; j < 4; ++j) {
            const int col = h0 + wc * 64 + j * 16 + l15;
            const floatx4 v = *(const floatx4*)&red[w4][1][j][lane * 4];
#pragma unroll
            for (int r = 0; r < 4; ++r)
                out[(size_t)(row0 + r) * HOUT + col] = acc[1][j][r] + v[r] + cj[j];
        }
    }
}

extern "C" void kernel_launch(void* const* d_in, const int* in_sizes, int n_in,
                              void* d_out, int out_size, void* d_ws, size_t ws_size,
                              hipStream_t stream) {
    const float* x = (const float*)d_in[0];
    const float* W = (const float*)d_in[1];
    const float* b = (const float*)d_in[2];
    float* out = (float*)d_out;

    unsigned short* Wfrag = (unsigned short*)d_ws;                      // 1,310,720 B
    float* c_part = (float*)((char*)d_ws + (size_t)NKT * 256 * 32 * 2); // 8 KB

    prep_kernel<<<4 * NKT + 8, 256, 0, stream>>>(W, b, Wfrag, c_part);
    kan_gemm<<<dim3(BDIM / BM, HOUT / BN), 512, 0, stream>>>(x, Wfrag, c_part, out);
}

// Round 5
// 106.852 us; speedup vs baseline: 1.4947x; 1.4947x over previous
//
#include <hip/hip_runtime.h>
#include <hip/hip_bf16.h>

// KAN harmonic-basis GEMM, v8: register-direct A-gen + global_load_lds B staging.
// out[b,h] = sum_{d,f} basis(x[b,d])[f] * W[d,f,h] + sum_d b[d,h]
//
// f=0 + bias -> fp32 partials c_part[8][256], summed in GEMM epilogue.
// f=1..10    -> bf16 MFMA GEMM, M=16384, N=256, K=2560.
//
// v8 (v7 post-mortem: asm VGPR ring at ~200-reg pressure risks RA spilling
// in-flight load destinations -> NaN; v4/v5: C++ rings get collapsed):
//   - B staged via __builtin_amdgcn_global_load_lds (DMA -> LDS, no dest
//     VGPRs to spill, pipeline cannot be shallowed by the compiler).
//     One copy per block -> B L2 traffic HALVED vs per-wave loads (wr pair
//     previously loaded identical fragments).
//   - T3 minimum 2-phase schedule (m248/m230): 16 phases x 5 kt, LDS
//     double-buffer 2 x 40,960 B = 81,920 B (exactly 2 blocks/CU). Per
//     phase: issue next stage -> compute 5 kt -> __syncthreads. Stage spans
//     a full compute phase (>> L2 latency) so the barrier drain is cheap.
//   - LDS fragment-linear: chunk (kt,f16cols) = 1KB, lane slot = lane*16B.
//     Achieved with per-lane pre-permuted GLOBAL source + linear LDS dest
//     (rule #21). Both ds_write (DMA) and ds_read_b128 conflict-free.
//   - A-gen register-direct per lane (v5 numerics: sincos + Chebyshev,
//     identical pack) -- no As LDS, no second barrier.

#define BDIM 16384
#define DDIM 256
#define HOUT 256
#define NKT  80
#define BM 64
#define BN 128

typedef __bf16 bf16x8 __attribute__((ext_vector_type(8)));
typedef float floatx4 __attribute__((ext_vector_type(4)));

__device__ __forceinline__ unsigned short f2bf(float f) {
    unsigned int u = __float_as_uint(f);
    return (unsigned short)((u + 0x7FFFu + ((u >> 16) & 1u)) >> 16);
}

__device__ __forceinline__ unsigned int pkbf(float a, float b) {
    __hip_bfloat162 r = __float22bfloat162_rn(make_float2(a, b));
    return *reinterpret_cast<unsigned int*>(&r);
}

// grid 328 x 256 threads.
// blocks [0,320): kt = bid>>2, sub = bid&3:
//   Wfrag[kt][n=t][dd = sub*8 .. +8] = bf16(W[dtile*32+dd][kt%10+1][n])
// blocks [320,328): p = bid-320; c_part[p][h] = sum_{d in p*32..+32} W[d][0][h]+b[d][h]
__global__ void prep_kernel(const float* __restrict__ W, const float* __restrict__ bias,
                            unsigned short* __restrict__ Wfrag, float* __restrict__ c_part) {
    const int bid = blockIdx.x;
    const int t = threadIdx.x;
    if (bid < 4 * NKT) {
        const int kt = bid >> 2;
        const int sub = bid & 3;
        const int dtile = kt / 10;
        const int f = kt - dtile * 10 + 1;
        const int d0 = dtile * 32 + sub * 8;
        const float* wsrc = W + ((size_t)d0 * 11 + f) * 256 + t;
        union { unsigned short s[8]; int4 v; } buf;
#pragma unroll
        for (int dd = 0; dd < 8; ++dd)
            buf.s[dd] = f2bf(wsrc[(size_t)dd * 11 * 256]);
        *(int4*)(Wfrag + ((size_t)kt * 256 + t) * 32 + sub * 8) = buf.v;
    } else {
        const int p = bid - 4 * NKT;
        float acc = 0.f;
#pragma unroll
        for (int dd = 0; dd < 32; ++dd) {
            const int d = p * 32 + dd;
            acc += W[(size_t)(d * 11) * 256 + t] + bias[(size_t)d * 256 + t];
        }
        c_part[p * 256 + t] = acc;
    }
}

// Stage one 5-kt phase (40,960 B) into lbuf. Chunk c in [0,40): ktl = c>>3,
// f = c&7 (16 cols). LDS dest linear (chunk base + lane*16B); global source
// per-lane permuted so lane slot l == (col l&15, dgroup l>>4) -- exactly the
// MFMA B-fragment slot this lane reads back.
__device__ __forceinline__ void stage_phase(const unsigned short* __restrict__ Wfrag,
                                            unsigned short* lbuf, int kt0,
                                            int h0, int wave, int l15, int koff) {
#pragma unroll
    for (int s = 0; s < 10; ++s) {
        const int c = wave * 10 + s;
        const int ktl = c >> 3;
        const int f = c & 7;
        const unsigned short* g = Wfrag + (size_t)(kt0 + ktl) * 8192
                                + (h0 + f * 16 + l15) * 32 + koff * 8;
        __builtin_amdgcn_global_load_lds((const void*)g, (void*)(lbuf + c * 512), 16, 0, 0);
    }
}

__global__ __launch_bounds__(256, 2)
void kan_gemm(const float* __restrict__ x, const unsigned short* __restrict__ Wfrag,
              const float* __restrict__ c_part, float* __restrict__ out) {
    __shared__ unsigned short Bs[2][5 * 8 * 512];   // 2 x 40,960 B -> 2 blocks/CU

    const int t = threadIdx.x;
    const int m0 = blockIdx.x * BM;
    const int h0 = blockIdx.y * BN;

    const int lane = t & 63;
    const int wave = t >> 6;
    const int wr = wave >> 1;        // row half (32 rows)
    const int wc = wave & 1;         // col half (64 cols)
    const int l15 = lane & 15;
    const int koff = lane >> 4;

    floatx4 acc[2][4];
#pragma unroll
    for (int i = 0; i < 2; ++i)
#pragma unroll
        for (int j = 0; j < 4; ++j)
            acc[i][j] = (floatx4){0.f, 0.f, 0.f, 0.f};

    // lane's x rows: i=0 -> m0 + wr*32 + l15, i=1 -> +16; d-slots koff*8..+8
    const float* xr0 = x + (size_t)(m0 + wr * 32 + l15) * DDIM + koff * 8;

    // x for dtile 0: [i*2 + half4]
    float4 xn[4];
    xn[0] = *(const float4*)(xr0 + 0);
    xn[1] = *(const float4*)(xr0 + 4);
    xn[2] = *(const float4*)(xr0 + 16 * DDIM + 0);
    xn[3] = *(const float4*)(xr0 + 16 * DDIM + 4);

    // prologue: stage phase 0 (kt 0..4) into Bs[0]
    stage_phase(Wfrag, &Bs[0][0], 0, h0, wave, l15, koff);
    __syncthreads();

    // Chebyshev state persists across the two phases of a dtile
    float sc[16], cc[16], sp[16], cp[16], t2c[16];

#pragma unroll
    for (int p = 0; p < 16; ++p) {
        const int dt = p >> 1;
        const int half = p & 1;
        const int buf = p & 1;

        // issue next phase's stage into the other buffer (spans this phase)
        if (p < 15)
            stage_phase(Wfrag, &Bs[buf ^ 1][0], (p + 1) * 5, h0, wave, l15, koff);

        if (half == 0) {
            // ---- gen init: sincos of 16 elems; Chebyshev state ----
#pragma unroll
            for (int i = 0; i < 2; ++i)
#pragma unroll
                for (int e = 0; e < 8; ++e) {
                    const int g = i * 8 + e;
                    const float xv = ((const float*)&xn[i * 2 + (e >> 2)])[e & 3];
                    __sincosf(xv, &sc[g], &cc[g]);
                    t2c[g] = cc[g] + cc[g];
                    sp[g] = 0.f;
                    cp[g] = 1.f;
                }
        }

        // ---- compute 5 kt of this phase ----
#pragma unroll
        for (int kl = 0; kl < 5; ++kl) {
            const int hs = half * 5 + kl;             // 0..9 within dtile
            const float* src = (hs & 1) ? cc : sc;    // even: sin(kx), odd: cos(kx)

            union { unsigned int u[4]; bf16x8 v; } a0, a1;
#pragma unroll
            for (int q = 0; q < 4; ++q) {
                a0.u[q] = pkbf(src[2 * q], src[2 * q + 1]);
                a1.u[q] = pkbf(src[8 + 2 * q], src[8 + 2 * q + 1]);
            }

            const unsigned short* fb = &Bs[buf][(kl * 8 + wc * 4) * 512 + lane * 8];
            const bf16x8 b0 = *(const bf16x8*)(fb);
            const bf16x8 b1 = *(const bf16x8*)(fb + 512);
            const bf16x8 b2 = *(const bf16x8*)(fb + 1024);
            const bf16x8 b3 = *(const bf16x8*)(fb + 1536);

            acc[0][0] = __builtin_amdgcn_mfma_f32_16x16x32_bf16(a0.v, b0, acc[0][0], 0, 0, 0);
            acc[1][0] = __builtin_amdgcn_mfma_f32_16x16x32_bf16(a1.v, b0, acc[1][0], 0, 0, 0);
            acc[0][1] = __builtin_amdgcn_mfma_f32_16x16x32_bf16(a0.v, b1, acc[0][1], 0, 0, 0);
            acc[1][1] = __builtin_amdgcn_mfma_f32_16x16x32_bf16(a1.v, b1, acc[1][1], 0, 0, 0);
            acc[0][2] = __builtin_amdgcn_mfma_f32_16x16x32_bf16(a0.v, b2, acc[0][2], 0, 0, 0);
            acc[1][2] = __builtin_amdgcn_mfma_f32_16x16x32_bf16(a1.v, b2, acc[1][2], 0, 0, 0);
            acc[0][3] = __builtin_amdgcn_mfma_f32_16x16x32_bf16(a0.v, b3, acc[0][3], 0, 0, 0);
            acc[1][3] = __builtin_amdgcn_mfma_f32_16x16x32_bf16(a1.v, b3, acc[1][3], 0, 0, 0);

            // advance harmonic after each cos emit (except the last)
            if ((hs & 1) && hs < 9) {
#pragma unroll
                for (int g = 0; g < 16; ++g) {
                    const float ns = t2c[g] * sc[g] - sp[g];
                    const float nc = t2c[g] * cc[g] - cp[g];
                    sp[g] = sc[g]; cp[g] = cc[g];
                    sc[g] = ns;   cc[g] = nc;
                }
            }
        }

        // x prefetch for the next dtile during its predecessor's second half
        if (half == 1 && dt < 7) {
            xn[0] = *(const float4*)(xr0 + (dt + 1) * 32 + 0);
            xn[1] = *(const float4*)(xr0 + (dt + 1) * 32 + 4);
            xn[2] = *(const float4*)(xr0 + 16 * DDIM + (dt + 1) * 32 + 0);
            xn[3] = *(const float4*)(xr0 + 16 * DDIM + (dt + 1) * 32 + 4);
        }

        __syncthreads();   // drains stage loads (issued a full phase ago) + swap
    }

    // ---- epilogue: C/D layout col=lane&15, row=(lane>>4)*4+reg ----
    float cj[4];
#pragma unroll
    for (int j = 0; j < 4; ++j) {
        const int col = h0 + wc * 64 + j * 16 + l15;
        float s = 0.f;
#pragma unroll
        for (int q = 0; q < 8; ++q) s += c_part[q * 256 + col];
        cj[j] = s;
    }
#pragma unroll
    for (int i = 0; i < 2; ++i) {
        const int row0 = m0 + wr * 32 + i * 16 + koff * 4;
#pragma unroll
        for (int j = 0; j < 4; ++j) {
            const int col = h0 + wc * 64 + j * 16 + l15;
#pragma unroll
            for (int r = 0; r < 4; ++r)
                out[(size_t)(row0 + r) * HOUT + col] = acc[i][j][r] + cj[j];
        }
    }
}

extern "C" void kernel_launch(void* const* d_in, const int* in_sizes, int n_in,
                              void* d_out, int out_size, void* d_ws, size_t ws_size,
                              hipStream_t stream) {
    const float* x = (const float*)d_in[0];
    const float* W = (const float*)d_in[1];
    const float* b = (const float*)d_in[2];
    float* out = (float*)d_out;

    unsigned short* Wfrag = (unsigned short*)d_ws;                      // 1,310,720 B
    float* c_part = (float*)((char*)d_ws + (size_t)NKT * 256 * 32 * 2); // 8 KB

    prep_kernel<<<4 * NKT + 8, 256, 0, stream>>>(W, b, Wfrag, c_part);
    kan_gemm<<<dim3(BDIM / BM, HOUT / BN), 256, 0, stream>>>(x, Wfrag, c_part, out);
}

// Round 6
// 105.274 us; speedup vs baseline: 1.5171x; 1.0150x over previous
//
#include <hip/hip_runtime.h>
#include <hip/hip_bf16.h>

// KAN harmonic-basis GEMM, v9: v8 + 8-wave blocks for 4 waves/SIMD TLP.
// out[b,h] = sum_{d,f} basis(x[b,d])[f] * W[d,f,h] + sum_d b[d,h]
//
// f=0 + bias -> fp32 partials c_part[8][256], summed in GEMM epilogue.
// f=1..10    -> bf16 MFMA GEMM, M=16384, N=256, K=2560.
//
// v9 (v8 post-mortem: 2-phase global_load_lds staging worked -- 52->46us,
// VALU 38%/MFMA 18%/occupancy 17.5%: still latency-bound, and the 512-block
// grid hard-caps residency at 2 waves/SIMD with 256-thread blocks):
//   - 512-thread blocks (8 waves = 4 wr x 2 wc), SAME BM=64 x BN=128 tile.
//     Per-wave work halves (1 i-frag x 4 j-frags, 8 trig elems); wave count
//     doubles -> all per-CU totals conserved (VALU, MFMA, B-DMA, trig dup)
//     but occupancy doubles to 4 waves/SIMD, the 4 waves on each SIMD coming
//     from 2 independent blocks (one block's barrier drain overlaps the
//     other's compute). Only LDS read traffic doubles (~21us busy on its own
//     pipe, under the target wall).
//   - __launch_bounds__(512,4) -> 2 blocks/CU, VGPR cap 128 (working set ~90,
//     no spill; v6's failure was a 200-reg working set at a 64-reg cap).
//   - Everything else identical to v8: 16 x 5-kt phases, LDS double buffer
//     2 x 40,960 B, fragment-linear DMA staging, register-direct A-gen.

#define BDIM 16384
#define DDIM 256
#define HOUT 256
#define NKT  80
#define BM 64
#define BN 128

typedef __bf16 bf16x8 __attribute__((ext_vector_type(8)));
typedef float floatx4 __attribute__((ext_vector_type(4)));

__device__ __forceinline__ unsigned short f2bf(float f) {
    unsigned int u = __float_as_uint(f);
    return (unsigned short)((u + 0x7FFFu + ((u >> 16) & 1u)) >> 16);
}

__device__ __forceinline__ unsigned int pkbf(float a, float b) {
    __hip_bfloat162 r = __float22bfloat162_rn(make_float2(a, b));
    return *reinterpret_cast<unsigned int*>(&r);
}

// grid 328 x 256 threads.
// blocks [0,320): kt = bid>>2, sub = bid&3:
//   Wfrag[kt][n=t][dd = sub*8 .. +8] = bf16(W[dtile*32+dd][kt%10+1][n])
// blocks [320,328): p = bid-320; c_part[p][h] = sum_{d in p*32..+32} W[d][0][h]+b[d][h]
__global__ void prep_kernel(const float* __restrict__ W, const float* __restrict__ bias,
                            unsigned short* __restrict__ Wfrag, float* __restrict__ c_part) {
    const int bid = blockIdx.x;
    const int t = threadIdx.x;
    if (bid < 4 * NKT) {
        const int kt = bid >> 2;
        const int sub = bid & 3;
        const int dtile = kt / 10;
        const int f = kt - dtile * 10 + 1;
        const int d0 = dtile * 32 + sub * 8;
        const float* wsrc = W + ((size_t)d0 * 11 + f) * 256 + t;
        union { unsigned short s[8]; int4 v; } buf;
#pragma unroll
        for (int dd = 0; dd < 8; ++dd)
            buf.s[dd] = f2bf(wsrc[(size_t)dd * 11 * 256]);
        *(int4*)(Wfrag + ((size_t)kt * 256 + t) * 32 + sub * 8) = buf.v;
    } else {
        const int p = bid - 4 * NKT;
        float acc = 0.f;
#pragma unroll
        for (int dd = 0; dd < 32; ++dd) {
            const int d = p * 32 + dd;
            acc += W[(size_t)(d * 11) * 256 + t] + bias[(size_t)d * 256 + t];
        }
        c_part[p * 256 + t] = acc;
    }
}

// Stage one 5-kt phase (40,960 B) into lbuf. Chunk c in [0,40): ktl = c>>3,
// f = c&7 (16 cols). LDS dest linear (chunk base + lane*16B); global source
// per-lane permuted so lane slot l == (col l&15, dgroup l>>4) -- exactly the
// MFMA B-fragment slot this lane reads back. 8 waves -> 5 chunks per wave.
__device__ __forceinline__ void stage_phase(const unsigned short* __restrict__ Wfrag,
                                            unsigned short* lbuf, int kt0,
                                            int h0, int wave, int l15, int koff) {
#pragma unroll
    for (int s = 0; s < 5; ++s) {
        const int c = wave * 5 + s;
        const int ktl = c >> 3;
        const int f = c & 7;
        const unsigned short* g = Wfrag + (size_t)(kt0 + ktl) * 8192
                                + (h0 + f * 16 + l15) * 32 + koff * 8;
        __builtin_amdgcn_global_load_lds((const void*)g, (void*)(lbuf + c * 512), 16, 0, 0);
    }
}

__global__ __launch_bounds__(512, 4)
void kan_gemm(const float* __restrict__ x, const unsigned short* __restrict__ Wfrag,
              const float* __restrict__ c_part, float* __restrict__ out) {
    __shared__ unsigned short Bs[2][5 * 8 * 512];   // 2 x 40,960 B -> 2 blocks/CU

    const int t = threadIdx.x;
    const int m0 = blockIdx.x * BM;
    const int h0 = blockIdx.y * BN;

    const int lane = t & 63;
    const int wave = t >> 6;         // 0..7
    const int wr = wave >> 1;        // i-frag: rows m0 + wr*16 .. +16
    const int wc = wave & 1;         // col half (64 cols, 4 j-frags)
    const int l15 = lane & 15;
    const int koff = lane >> 4;

    floatx4 acc[4];
#pragma unroll
    for (int j = 0; j < 4; ++j)
        acc[j] = (floatx4){0.f, 0.f, 0.f, 0.f};

    // lane's x row: m0 + wr*16 + l15; d-slots koff*8..+8
    const float* xr0 = x + (size_t)(m0 + wr * 16 + l15) * DDIM + koff * 8;

    // x for dtile 0 (8 floats)
    float4 xn[2];
    xn[0] = *(const float4*)(xr0 + 0);
    xn[1] = *(const float4*)(xr0 + 4);

    // prologue: stage phase 0 (kt 0..4) into Bs[0]
    stage_phase(Wfrag, &Bs[0][0], 0, h0, wave, l15, koff);
    __syncthreads();

    // Chebyshev state persists across the two phases of a dtile
    float sc[8], cc[8], sp[8], cp[8], t2c[8];

#pragma unroll
    for (int p = 0; p < 16; ++p) {
        const int dt = p >> 1;
        const int half = p & 1;
        const int buf = p & 1;

        // issue next phase's stage into the other buffer (spans this phase)
        if (p < 15)
            stage_phase(Wfrag, &Bs[buf ^ 1][0], (p + 1) * 5, h0, wave, l15, koff);

        if (half == 0) {
            // ---- gen init: sincos of 8 elems; Chebyshev state ----
#pragma unroll
            for (int e = 0; e < 8; ++e) {
                const float xv = ((const float*)&xn[e >> 2])[e & 3];
                __sincosf(xv, &sc[e], &cc[e]);
                t2c[e] = cc[e] + cc[e];
                sp[e] = 0.f;
                cp[e] = 1.f;
            }
        }

        // ---- compute 5 kt of this phase ----
#pragma unroll
        for (int kl = 0; kl < 5; ++kl) {
            const int hs = half * 5 + kl;             // 0..9 within dtile
            const float* src = (hs & 1) ? cc : sc;    // even: sin(kx), odd: cos(kx)

            union { unsigned int u[4]; bf16x8 v; } a0;
#pragma unroll
            for (int q = 0; q < 4; ++q)
                a0.u[q] = pkbf(src[2 * q], src[2 * q + 1]);

            const unsigned short* fb = &Bs[buf][(kl * 8 + wc * 4) * 512 + lane * 8];
            const bf16x8 b0 = *(const bf16x8*)(fb);
            const bf16x8 b1 = *(const bf16x8*)(fb + 512);
            const bf16x8 b2 = *(const bf16x8*)(fb + 1024);
            const bf16x8 b3 = *(const bf16x8*)(fb + 1536);

            acc[0] = __builtin_amdgcn_mfma_f32_16x16x32_bf16(a0.v, b0, acc[0], 0, 0, 0);
            acc[1] = __builtin_amdgcn_mfma_f32_16x16x32_bf16(a0.v, b1, acc[1], 0, 0, 0);
            acc[2] = __builtin_amdgcn_mfma_f32_16x16x32_bf16(a0.v, b2, acc[2], 0, 0, 0);
            acc[3] = __builtin_amdgcn_mfma_f32_16x16x32_bf16(a0.v, b3, acc[3], 0, 0, 0);

            // advance harmonic after each cos emit (except the last)
            if ((hs & 1) && hs < 9) {
#pragma unroll
                for (int e = 0; e < 8; ++e) {
                    const float ns = t2c[e] * sc[e] - sp[e];
                    const float nc = t2c[e] * cc[e] - cp[e];
                    sp[e] = sc[e]; cp[e] = cc[e];
                    sc[e] = ns;   cc[e] = nc;
                }
            }
        }

        // x prefetch for the next dtile during its predecessor's second half
        if (half == 1 && dt < 7) {
            xn[0] = *(const float4*)(xr0 + (dt + 1) * 32 + 0);
            xn[1] = *(const float4*)(xr0 + (dt + 1) * 32 + 4);
        }

        __syncthreads();   // drains stage loads (issued a full phase ago) + swap
    }

    // ---- epilogue: C/D layout col=lane&15, row=(lane>>4)*4+reg ----
    float cj[4];
#pragma unroll
    for (int j = 0; j < 4; ++j) {
        const int col = h0 + wc * 64 + j * 16 + l15;
        float s = 0.f;
#pragma unroll
        for (int q = 0; q < 8; ++q) s += c_part[q * 256 + col];
        cj[j] = s;
    }
    const int row0 = m0 + wr * 16 + koff * 4;
#pragma unroll
    for (int j = 0; j < 4; ++j) {
        const int col = h0 + wc * 64 + j * 16 + l15;
#pragma unroll
        for (int r = 0; r < 4; ++r)
            out[(size_t)(row0 + r) * HOUT + col] = acc[j][r] + cj[j];
    }
}

extern "C" void kernel_launch(void* const* d_in, const int* in_sizes, int n_in,
                              void* d_out, int out_size, void* d_ws, size_t ws_size,
                              hipStream_t stream) {
    const float* x = (const float*)d_in[0];
    const float* W = (const float*)d_in[1];
    const float* b = (const float*)d_in[2];
    float* out = (float*)d_out;

    unsigned short* Wfrag = (unsigned short*)d_ws;                      // 1,310,720 B
    float* c_part = (float*)((char*)d_ws + (size_t)NKT * 256 * 32 * 2); // 8 KB

    prep_kernel<<<4 * NKT + 8, 256, 0, stream>>>(W, b, Wfrag, c_part);
    kan_gemm<<<dim3(BDIM / BM, HOUT / BN), 512, 0, stream>>>(x, Wfrag, c_part, out);
}